// Round 4
// baseline (243.014 us; speedup 1.0000x reference)
//
#include <hip/hip_runtime.h>

#define T_DIM 60
#define NBLK 3840                 // NT / 256 (983040), elements per block = 256

typedef float v4f __attribute__((ext_vector_type(4)));
typedef float v2f __attribute__((ext_vector_type(2)));

// Fused single-pass kernel. Block handles 256 CONSECUTIVE elements (n*T+t).
// v5 changes vs v4 (227.6 µs):
//  - NO nontemporal hints. v1..v4 all plateaued at ~2.75 TB/s read with nt
//    on every bulk load, insensitive to scheduling structure (prefetch-all,
//    barrier placement, divergence all neutral). Plain-load streaming
//    kernels on this chip sustain 5.2-5.4 TB/s. nt forces the full
//    no-allocate HBM path on every request; with a bounded per-CU
//    in-flight budget, longer latency = proportionally less BW.
//  - Occupancy doubled: lean loop (no prefetch arrays, per-it atomics —
//    structure proven perf-neutral in v2 vs v3/v4), __launch_bounds__(256,8)
//    caps at 64 VGPR -> 32 waves/CU (v3/v4 register pressure allowed 16).
//    Latency hiding via TLP, like the 5+ TB/s reference kernels.
//  - keeps: LDS staging of x/mask/pi, single barrier (lsepi from a
//    redundant direct pi read), rcp/rsq closed-form 2x2 math, deferred
//    final reduce via atomicAdd.
__global__ __launch_bounds__(256, 8)
void loss_fused_kernel(const float* __restrict__ mu,
                       const float* __restrict__ sigma,
                       const float* __restrict__ pi,
                       const float* __restrict__ x,
                       const float* __restrict__ mask,
                       float* __restrict__ loss_p,
                       float* __restrict__ mask_p,
                       float* __restrict__ out) {
    __shared__ float bl[T_DIM], bm[T_DIM];
    __shared__ float s_lsepi[8];
    __shared__ float s_piv[48];       // <=6 pi rows, value - LOG_2PI
    __shared__ v2f   s_x[256];
    __shared__ float s_mk[256];
    const float LOG_2PI = 1.8378770664093453f;
    int tid = threadIdx.x;
    int E0 = blockIdx.x * 256;
    int n_base = E0 / T_DIM;
    int ncnt = (E0 + 255) / T_DIM - n_base + 1;   // <= 6

    // ---- Phase 1: staging (plain coalesced loads) + ONE barrier ----
    if (tid < T_DIM) { bl[tid] = 0.0f; bm[tid] = 0.0f; }
    s_x[tid]  = ((const v2f*)x)[E0 + tid];
    s_mk[tid] = mask[E0 + tid];
    if (tid < 8 * ncnt)
        s_piv[tid] = pi[(size_t)n_base * 8 + tid] - LOG_2PI;
    if (tid < ncnt) {
        // redundant direct read of the pi row (8 floats, L2-hot) so the
        // LSE needs no intermediate barrier on s_piv
        const float* pr = pi + (size_t)(n_base + tid) * 8;
        float q0 = pr[0], q1 = pr[1], q2 = pr[2], q3 = pr[3];
        float q4 = pr[4], q5 = pr[5], q6 = pr[6], q7 = pr[7];
        float mx = fmaxf(fmaxf(fmaxf(q0, q1), fmaxf(q2, q3)),
                         fmaxf(fmaxf(q4, q5), fmaxf(q6, q7)));
        float s = __expf(q0 - mx) + __expf(q1 - mx) + __expf(q2 - mx) +
                  __expf(q3 - mx) + __expf(q4 - mx) + __expf(q5 - mx) +
                  __expf(q6 - mx) + __expf(q7 - mx);
        s_lsepi[tid] = mx + __logf(s);           // lse of RAW pi row
    }
    if (blockIdx.x == 0 && tid == 0) out[0] = 0.0f;
    __syncthreads();

    // ---- Phase 2: lean compute loop, latency hidden by 32 waves/CU ----
    int l = tid & 7;                  // owned mixture component
    int oct = tid >> 3;               // 0..31
    int e = E0 + oct;                 // global element, += 32 per it
    int idx = oct;                    // element - E0 (LDS index)
    int n0 = e / T_DIM;
    int t = e - n0 * T_DIM;
    int nb = n0 - n_base;

#pragma unroll
    for (int it = 0; it < 8; ++it) {
        v4f sg = ((const v4f*)sigma)[(size_t)e * 8 + l];   // 1KB/wave, coalesced
        v2f m2 = ((const v2f*)mu)[(size_t)e * 8 + l];      // 512B/wave
        v2f xv = s_x[idx];            // broadcast within octet, conflict-free
        float mk = s_mk[idx];
        float pv = s_piv[nb * 8 + l]; // pi - LOG_2PI

        // closed-form 2x2: det = ac-b^2, maha = (c d1^2 - 2b d1 d2 + a d2^2)/det
        float a = sg.x, b = sg.y, c = sg.w;
        float d1 = xv.x - m2.x, d2 = xv.y - m2.y;
        float det = a * c - b * b;                     // >= 0.25 (SPD + 0.5I)
        float rdet = __builtin_amdgcn_rcpf(det);
        float maha = (c * d1 * d1 - 2.0f * b * d1 * d2 + a * d2 * d2) * rdet;
        // component density term: exp(pv - 0.5*maha) / sqrt(det)
        float g = __expf(__builtin_fmaf(-0.5f, maha, pv)) *
                  __builtin_amdgcn_rsqf(det);

        // sum over the 8 components (all positive, bounded ~1e2)
        float s = g;
        s += __shfl_xor(s, 1);
        s += __shfl_xor(s, 2);
        s += __shfl_xor(s, 4);

        if (l == 0) {
            float v = (s_lsepi[nb] - __logf(s)) * mk;  // -gmm_lp * mask
            atomicAdd(&bl[t], v);
            atomicAdd(&bm[t], mk);
        }

        e += 32;
        idx += 32;
        t += 32;
        if (t >= T_DIM) { t -= T_DIM; nb += 1; }       // cndmask, no branch
    }
    __syncthreads();
    if (tid < T_DIM) {
        loss_p[(size_t)tid * NBLK + blockIdx.x] = bl[tid];
        mask_p[(size_t)tid * NBLK + blockIdx.x] = bm[tid];
    }
}

// 60 blocks: block t sums its coalesced partial row, atomically accumulates
// t_loss/npred into out[0] (zeroed by loss_fused_kernel, stream-ordered).
__global__ void reduce_t_kernel(const float* __restrict__ loss_p,
                                const float* __restrict__ mask_p,
                                float* __restrict__ out, int nblocks) {
    int t = blockIdx.x;
    const float* lrow = loss_p + (size_t)t * nblocks;
    const float* mrow = mask_p + (size_t)t * nblocks;
    float sl = 0.0f, sm = 0.0f;
    for (int i = threadIdx.x; i < nblocks; i += blockDim.x) {
        sl += lrow[i]; sm += mrow[i];
    }
#pragma unroll
    for (int off = 32; off > 0; off >>= 1) {
        sl += __shfl_down(sl, off); sm += __shfl_down(sm, off);
    }
    __shared__ float wl[4], wm[4];
    int lane = threadIdx.x & 63, w = threadIdx.x >> 6;
    if (lane == 0) { wl[w] = sl; wm[w] = sm; }
    __syncthreads();
    if (threadIdx.x == 0)
        atomicAdd(out, (wl[0] + wl[1] + wl[2] + wl[3]) /
                       (wm[0] + wm[1] + wm[2] + wm[3]));
}

extern "C" void kernel_launch(void* const* d_in, const int* in_sizes, int n_in,
                              void* d_out, int out_size, void* d_ws, size_t ws_size,
                              hipStream_t stream) {
    const float* mu    = (const float*)d_in[0];   // (N,T,M,K)
    const float* sigma = (const float*)d_in[1];   // (N,T,M,K,K)
    const float* pi    = (const float*)d_in[2];   // (N,M)
    const float* x     = (const float*)d_in[3];   // (N,T,K)
    const float* mask  = (const float*)d_in[4];   // (N,T)
    float* out = (float*)d_out;
    float* ws = (float*)d_ws;
    // ws layout (1.8 MB of ~480 MB): loss_p | mask_p
    float* loss_p = ws;
    float* mask_p = ws + (size_t)T_DIM * NBLK;

    hipLaunchKernelGGL(loss_fused_kernel, dim3(NBLK), dim3(256), 0, stream,
                       mu, sigma, pi, x, mask, loss_p, mask_p, out);
    hipLaunchKernelGGL(reduce_t_kernel, dim3(T_DIM), dim3(256), 0, stream,
                       loss_p, mask_p, out, NBLK);
}